// Round 2
// baseline (113.050 us; speedup 1.0000x reference)
//
#include <hip/hip_runtime.h>

#define NN   2048
#define CC   64
#define TT   64
#define ROWS 4
#define BHN  (16 * 2048)

__global__ __launch_bounds__(256, 4) void cope_kernel(
    const float* __restrict__ q,
    const float* __restrict__ qk,
    const float* __restrict__ pos_emb,
    float* __restrict__ out)
{
    const int tid  = threadIdx.x;      // [0,256)
    const int lane = tid & 63;
    const int wv   = tid >> 6;         // wave id 0..3
    const int row0 = blockIdx.x * ROWS;

    __shared__ float e_row[ROWS][TT];
    __shared__ float wave_tot[ROWS][4];

    // ---- issue ALL qk loads upfront: 2 float4 per row, 4 rows ----
    float4 v[2 * ROWS];
#pragma unroll
    for (int r = 0; r < ROWS; ++r) {
        const float4* qk4 = (const float4*)(qk + (size_t)(row0 + r) * NN);
        v[2 * r]     = qk4[2 * tid];
        v[2 * r + 1] = qk4[2 * tid + 1];
    }

    // ---- per-wave solo E: wave wv computes e_row[wv][t], t = lane ----
    {
        const int erow = __builtin_amdgcn_readfirstlane(row0 + wv);
        const float* qr = q + (size_t)erow * CC;   // wave-uniform -> scalar loads
        float acc0 = 0.0f, acc1 = 0.0f;
#pragma unroll 8
        for (int c = 0; c < CC; c += 2) {
            acc0 = fmaf(qr[c],     pos_emb[c * TT + lane],       acc0);
            acc1 = fmaf(qr[c + 1], pos_emb[(c + 1) * TT + lane], acc1);
        }
        e_row[wv][lane] = acc0 + acc1;
    }

    // ---- sigmoid of all 32 elements (4 rows x 8) ----
    float g[8 * ROWS];
#pragma unroll
    for (int r = 0; r < ROWS; ++r) {
        g[8 * r + 0] = v[2 * r].x;     g[8 * r + 1] = v[2 * r].y;
        g[8 * r + 2] = v[2 * r].z;     g[8 * r + 3] = v[2 * r].w;
        g[8 * r + 4] = v[2 * r + 1].x; g[8 * r + 5] = v[2 * r + 1].y;
        g[8 * r + 6] = v[2 * r + 1].z; g[8 * r + 7] = v[2 * r + 1].w;
    }
#pragma unroll
    for (int k = 0; k < 8 * ROWS; ++k)
        g[k] = __builtin_amdgcn_rcpf(1.0f + __expf(-g[k]));

    // ---- per-row wave-level suffix scan of thread-chunk sums ----
    float X[ROWS];
#pragma unroll
    for (int r = 0; r < ROWS; ++r) {
        float s = 0.0f;
#pragma unroll
        for (int k = 0; k < 8; ++k) s += g[8 * r + k];
        float inc = s;
#pragma unroll
        for (int o = 1; o < 64; o <<= 1) {
            float tmp = __shfl_down(inc, o, 64);
            if (lane + o < 64) inc += tmp;
        }
        X[r] = inc - s;                       // exclusive suffix within wave
        if (lane == 0) wave_tot[r][wv] = inc; // wave total
    }

    __syncthreads();   // publishes e_row[*] and wave_tot[*]

    // ---- per row: combine, local suffix, clamp, gather-interp, store ----
#pragma unroll
    for (int r = 0; r < ROWS; ++r) {
        float W = 0.0f;
#pragma unroll
        for (int w2 = 0; w2 < 4; ++w2)
            if (w2 > wv) W += wave_tot[r][w2];
        const float base = X[r] + W;

        float o8[8];
        float run = 0.0f;
#pragma unroll
        for (int k = 7; k >= 0; --k) {
            run += g[8 * r + k];
            float P  = fminf(run + base, 63.0f);
            float fl = floorf(P);
            float w_ = P - fl;
            int   i0 = (int)fl;
            int   i1 = (int)ceilf(P);
            float ef = e_row[r][i0];
            float ec = e_row[r][i1];
            o8[k] = fmaf(w_, ec - ef, ef);
        }

        float4* out4 = (float4*)(out + (size_t)(row0 + r) * NN);
        out4[2 * tid]     = make_float4(o8[0], o8[1], o8[2], o8[3]);
        out4[2 * tid + 1] = make_float4(o8[4], o8[5], o8[6], o8[7]);
    }
}

extern "C" void kernel_launch(void* const* d_in, const int* in_sizes, int n_in,
                              void* d_out, int out_size, void* d_ws, size_t ws_size,
                              hipStream_t stream) {
    const float* q       = (const float*)d_in[0];
    const float* qk      = (const float*)d_in[1];
    const float* pos_emb = (const float*)d_in[2];
    float* out = (float*)d_out;

    dim3 grid(BHN / ROWS);   // 8192 blocks
    dim3 block(256);
    cope_kernel<<<grid, block, 0, stream>>>(q, qk, pos_emb, out);
}